// Round 1
// 455.388 us; speedup vs baseline: 1.0273x; 1.0273x over previous
//
#include <hip/hip_runtime.h>
#include <hip/hip_bf16.h>
#include <stdint.h>

// Problem constants: M=512, P=256, B=128, T=1024
#define NB   128
#define NT   1024
#define NM   512
#define NP   256

typedef __attribute__((ext_vector_type(8))) short bf16x8;
typedef __attribute__((ext_vector_type(4))) float f32x4;
typedef unsigned int u32;

// pack two f32 -> two bf16 in one u32 (round-half-up; bias << bf16 ulp)
__device__ __forceinline__ uint32_t bfpair(float a, float b) {
    uint32_t ua = __float_as_uint(a) + 0x8000u;
    uint32_t ub = __float_as_uint(b) + 0x8000u;
    return __builtin_amdgcn_perm(ub, ua, 0x07060302u);
}

__device__ __forceinline__ float fast_tanh(float x) {
    float e = __expf(2.0f * x);                       // inf-safe
    return 1.0f - 2.0f * __builtin_amdgcn_rcpf(e + 1.0f);
}

// async global->LDS DMA, 16 B per lane; LDS dest = wave-uniform base + lane*16
typedef const __attribute__((address_space(1))) u32* gas_t;
typedef __attribute__((address_space(3))) u32* las_t;
__device__ __forceinline__ void dma16(const void* g, void* l) {
    __builtin_amdgcn_global_load_lds((gas_t)g, (las_t)l, 16, 0, 0);
}

// ---------- prep: 0..255 cvt U->bf16 | 256..383 wq GEMV | 384..511 zero d_out ----------
__global__ void prep_kernel(const float* __restrict__ U, unsigned short* __restrict__ Ub,
                            const float* __restrict__ d_t, const float* __restrict__ s_t,
                            const float* __restrict__ W, float* __restrict__ wq,
                            float* __restrict__ out) {
    const int bx = blockIdx.x;
    if (bx < 256) {
        int idx = bx * 256 + threadIdx.x;                  // 65536 threads, 1 float4 each
        float4 u = reinterpret_cast<const float4*>(U)[idx];
        reinterpret_cast<uint2*>(Ub)[idx] = make_uint2(bfpair(u.x, u.y), bfpair(u.z, u.w));
    } else if (bx < 384) {
        int g = (bx - 256) * 512 + threadIdx.x * 2;        // 2 outputs/thread -> 65536
        int b = g >> 9;
        const float* dt = d_t + (size_t)b * NP;
        const float* st = s_t + (size_t)b * NP;
        #pragma unroll
        for (int e = 0; e < 2; ++e) {
            int n = (g + e) & 511;
            const float* Wn = W + (size_t)n * 512;
            float s = 0.f;
            #pragma unroll 4
            for (int c = 0; c < NP; c += 4) {
                float4 w0 = *reinterpret_cast<const float4*>(Wn + c);
                float4 q0 = *reinterpret_cast<const float4*>(dt + c);
                s += w0.x * q0.x + w0.y * q0.y + w0.z * q0.z + w0.w * q0.w;
                float4 w1 = *reinterpret_cast<const float4*>(Wn + NP + c);
                float4 q1 = *reinterpret_cast<const float4*>(st + c);
                s += w1.x * q1.x + w1.y * q1.y + w1.z * q1.z + w1.w * q1.w;
            }
            wq[g + e] = s;
        }
    } else {
        int idx = (bx - 384) * 256 + threadIdx.x;          // 32768 float4 = 128K floats
        reinterpret_cast<float4*>(out)[idx] = make_float4(0.f, 0.f, 0.f, 0.f);
    }
}

// ---------- score: 128t x 256n per WG ----------
// grid 2048 1-D, swizzled: g=id>>4, p=id&7, nh=(id>>3)&1; tile=g*8+p (tt=tile&7, b=tile>>3)
// -> both nh of a tile get ids differing by 8 => same XCD (id%8) => share H lines in L2.
// waves: w>>1 = t-half (64 rows), w&1 = n-half (128 cols). acc 4x8 f32x4 = 128 AGPR.
//
// v2 pipeline (T3/T4-style counted vmcnt, raw barriers):
//   A (H tile): global->reg (issued 1 iter early) -> bf16 convert -> ds_write, As double-buf
//   B (Ub):     global_load_lds DMA, Bs TRIPLE-buf, depth-2 prefetch; vmcnt(8) not 0 at barrier
// LDS layout (both bf16, row = 64 B = 4 chunks of 16 B):
//   chunk c of row r lives at slot c ^ ((r>>1)&3)  (involution; read applies same XOR)
__global__ __launch_bounds__(256, 2)
void score_kernel(const float* __restrict__ H, const unsigned short* __restrict__ Ub,
                  const float* __restrict__ wq, const float* __restrict__ v_d,
                  float* __restrict__ out) {
    __shared__ unsigned short As[2][128 * 32];     //  8 KB/buf, bf16, swizzled
    __shared__ unsigned short Bs[3][256 * 32];     // 16 KB/buf, bf16, swizzled
    __shared__ float s_score[128];                 // total LDS = 66048 B (2 blocks/CU)

    const int tid  = threadIdx.x;
    const int id   = blockIdx.x;
    const int tile = (id >> 4) * 8 + (id & 7);
    const int nh   = (id >> 3) & 1;
    const int tt   = tile & 7;
    const int b    = tile >> 3;

    const int lane = tid & 63;
    const int w    = tid >> 6;
    const int lr   = lane & 15;
    const int lq   = lane >> 4;
    const int tw   = w >> 1;
    const int nw   = w & 1;

    if (tid < 128) s_score[tid] = 0.f;

    // ---- A staging: each thread owns 4 rows (spaced 8), float4 at col (lane&7)*4 ----
    const float* gA[4];
    u32 woff[4];
    #pragma unroll
    for (int q = 0; q < 4; ++q) {
        int r = w * 32 + q * 8 + (lane >> 3);
        gA[q] = H + ((size_t)(b * NT + tt * 128 + r)) * NM + (lane & 7) * 4;
        // write 8 B: 16B-chunk c=(lane&7)>>1 at slot c^((r>>1)&3), half (lane&1)*8
        woff[q] = (u32)(r * 64 + ((((lane & 7) >> 1) ^ ((r >> 1) & 3)) << 4) + (lane & 1) * 8);
    }
    // ---- B DMA: per-lane source pre-swizzled so linear LDS dest lands swizzled ----
    const unsigned short* gB[4];
    u32 lB[4];
    #pragma unroll
    for (int q = 0; q < 4; ++q) {
        int rB = w * 64 + q * 16 + (lane >> 2);
        int cB = (lane & 3) ^ ((rB >> 1) & 3);
        gB[q] = Ub + ((size_t)(nh * 256 + rB)) * NM + cB * 8;
        lB[q] = (u32)((w * 4 + q) * 1024 + lane * 16);
    }
    // frag read offsets: slot = lq ^ ((row>>1)&3); row strides of 16 -> +1024 B per frag
    const u32 aro = (u32)((tw * 64 + lr) * 64 + ((lq ^ ((lr >> 1) & 3)) << 4));
    const u32 bro = (u32)((nw * 128 + lr) * 64 + ((lq ^ ((lr >> 1) & 3)) << 4));

    f32x4 acc[4][8];
    #pragma unroll
    for (int i = 0; i < 4; ++i)
        #pragma unroll
        for (int j = 0; j < 8; ++j)
            acc[i][j] = (f32x4){0.f, 0.f, 0.f, 0.f};

    float4 av[4];
    // ---- prologue: Aload(0); dmaB(0); cvt A(0)->As[0]; Aload(1); dmaB(1) ----
    #pragma unroll
    for (int q = 0; q < 4; ++q) { av[q] = *reinterpret_cast<const float4*>(gA[q]); gA[q] += 32; }
    #pragma unroll
    for (int q = 0; q < 4; ++q) { dma16(gB[q], (char*)Bs[0] + lB[q]); gB[q] += 32; }
    #pragma unroll
    for (int q = 0; q < 4; ++q)
        *reinterpret_cast<uint2*>((char*)As[0] + woff[q]) =
            make_uint2(bfpair(av[q].x, av[q].y), bfpair(av[q].z, av[q].w));
    #pragma unroll
    for (int q = 0; q < 4; ++q) { av[q] = *reinterpret_cast<const float4*>(gA[q]); gA[q] += 32; }
    #pragma unroll
    for (int q = 0; q < 4; ++q) { dma16(gB[q], (char*)Bs[1] + lB[q]); gB[q] += 32; }

    // need dmaB(0) done; keep Aload(1)+dmaB(1) (8 ops) in flight
    asm volatile("s_waitcnt vmcnt(8)" ::: "memory");
    asm volatile("s_waitcnt lgkmcnt(0)" ::: "memory");
    __builtin_amdgcn_s_barrier();
    __builtin_amdgcn_sched_barrier(0);

    #pragma unroll
    for (int kk = 0; kk < 16; ++kk) {
        // A fragments (rows tw*64 + i*16 + lr, k = lq*8..+8)
        const char* ab = (const char*)As[kk & 1] + aro;
        bf16x8 a0 = *reinterpret_cast<const bf16x8*>(ab);
        bf16x8 a1 = *reinterpret_cast<const bf16x8*>(ab + 1024);
        bf16x8 a2 = *reinterpret_cast<const bf16x8*>(ab + 2048);
        bf16x8 a3 = *reinterpret_cast<const bf16x8*>(ab + 3072);

        // write A(kk+1) into the other As buffer (av loaded one iteration ago;
        // compiler auto-waits vmcnt(4) = dmaB(kk+1) still outstanding)
        if (kk < 15) {
            char* an = (char*)As[(kk + 1) & 1];
            #pragma unroll
            for (int q = 0; q < 4; ++q)
                *reinterpret_cast<uint2*>(an + woff[q]) =
                    make_uint2(bfpair(av[q].x, av[q].y), bfpair(av[q].z, av[q].w));
        }
        // issue depth-2 prefetch: Aload(kk+2) -> regs, dmaB(kk+2) -> Bs[(kk+2)%3]
        if (kk < 14) {
            #pragma unroll
            for (int q = 0; q < 4; ++q) { av[q] = *reinterpret_cast<const float4*>(gA[q]); gA[q] += 32; }
            char* bn = (char*)Bs[(kk + 2) % 3];
            #pragma unroll
            for (int q = 0; q < 4; ++q) { dma16(gB[q], bn + lB[q]); gB[q] += 32; }
        }

        // B fragments + MFMA; one bb live at a time to cap VGPR pressure
        const char* bbb = (const char*)Bs[kk % 3] + bro;
        #pragma unroll
        for (int j = 0; j < 8; ++j) {
            bf16x8 bbj = *reinterpret_cast<const bf16x8*>(bbb + j * 1024);
            acc[0][j] = __builtin_amdgcn_mfma_f32_16x16x32_bf16(a0, bbj, acc[0][j], 0, 0, 0);
            acc[1][j] = __builtin_amdgcn_mfma_f32_16x16x32_bf16(a1, bbj, acc[1][j], 0, 0, 0);
            acc[2][j] = __builtin_amdgcn_mfma_f32_16x16x32_bf16(a2, bbj, acc[2][j], 0, 0, 0);
            acc[3][j] = __builtin_amdgcn_mfma_f32_16x16x32_bf16(a3, bbj, acc[3][j], 0, 0, 0);
        }

        // barrier for iter kk+1: dmaB(kk+1) must be done, but dmaB(kk+2)+Aload(kk+2)
        // (8 newest ops) STAY IN FLIGHT across the barrier -> counted vmcnt, never 0
        if (kk < 14) {
            asm volatile("s_waitcnt vmcnt(8)" ::: "memory");
        } else if (kk == 14) {
            asm volatile("s_waitcnt vmcnt(0)" ::: "memory");
        }
        if (kk < 15) {
            asm volatile("s_waitcnt lgkmcnt(0)" ::: "memory");
            __builtin_amdgcn_s_barrier();
            __builtin_amdgcn_sched_barrier(0);
        }
    }

    // epilogue: acc[i][j][r] at t = tt*128 + tw*64 + i*16 + lq*4 + r, n = nh*256 + nw*128 + j*16 + lr
    const float* wqb = wq + (size_t)b * NM;
    float vv[8], wv[8];
    #pragma unroll
    for (int j = 0; j < 8; ++j) {
        int n = nh * 256 + nw * 128 + j * 16 + lr;
        vv[j] = v_d[n];
        wv[j] = wqb[n];
    }
    #pragma unroll
    for (int i = 0; i < 4; ++i) {
        #pragma unroll
        for (int r = 0; r < 4; ++r) {
            float s = 0.f;
            #pragma unroll
            for (int j = 0; j < 8; ++j)
                s += vv[j] * fast_tanh(wv[j] + acc[i][j][r]);
            #pragma unroll
            for (int off = 1; off < 16; off <<= 1)
                s += __shfl_xor(s, off, 64);
            if (lr == 0) atomicAdd(&s_score[tw * 64 + i * 16 + lq * 4 + r], s);
        }
    }
    __syncthreads();
    if (tid < 128) atomicAdd(&out[(size_t)b * NT + tt * 128 + tid], s_score[tid]);
}

// ---------- softmax over T=1024, in place, one WG per b ----------
__global__ void softmax_kernel(float* __restrict__ out) {
    const int b   = blockIdx.x;
    const int tid = threadIdx.x;          // 256 threads x 4 elems
    float* p = out + (size_t)b * NT;
    float4 v = reinterpret_cast<float4*>(p)[tid];
    float m = fmaxf(fmaxf(v.x, v.y), fmaxf(v.z, v.w));
    #pragma unroll
    for (int off = 32; off >= 1; off >>= 1)
        m = fmaxf(m, __shfl_xor(m, off, 64));
    __shared__ float red[8];
    const int wv = tid >> 6;
    if ((tid & 63) == 0) red[wv] = m;
    __syncthreads();
    m = fmaxf(fmaxf(red[0], red[1]), fmaxf(red[2], red[3]));
    float e0 = __expf(v.x - m), e1 = __expf(v.y - m);
    float e2 = __expf(v.z - m), e3 = __expf(v.w - m);
    float s = e0 + e1 + e2 + e3;
    #pragma unroll
    for (int off = 32; off >= 1; off >>= 1)
        s += __shfl_xor(s, off, 64);
    if ((tid & 63) == 0) red[4 + wv] = s;
    __syncthreads();
    s = red[4] + red[5] + red[6] + red[7];
    float inv = 1.f / s;
    float4 o;
    o.x = e0 * inv; o.y = e1 * inv; o.z = e2 * inv; o.w = e3 * inv;
    reinterpret_cast<float4*>(p)[tid] = o;
}

extern "C" void kernel_launch(void* const* d_in, const int* in_sizes, int n_in,
                              void* d_out, int out_size, void* d_ws, size_t ws_size,
                              hipStream_t stream) {
    const float* d_t = (const float*)d_in[0];
    const float* s_t = (const float*)d_in[1];
    const float* H   = (const float*)d_in[2];
    // d_in[3] = T (scalar, 1024) — shapes hard-coded
    const float* W_d = (const float*)d_in[4];
    const float* U_d = (const float*)d_in[5];
    const float* v_d = (const float*)d_in[6];
    float* out = (float*)d_out;

    unsigned short* Ub = (unsigned short*)d_ws;              // 512 KB bf16 U
    float* wq = (float*)((char*)d_ws + 512 * 1024);          // 256 KB fp32 wq

    prep_kernel<<<512, 256, 0, stream>>>(U_d, Ub, d_t, s_t, W_d, wq, out);
    score_kernel<<<2048, 256, 0, stream>>>(H, Ub, wq, v_d, out);
    softmax_kernel<<<NB, 256, 0, stream>>>(out);
}